// Round 1
// baseline (625.046 us; speedup 1.0000x reference)
//
#include <hip/hip_runtime.h>
#include <hip/hip_bf16.h>
#include <math.h>

// Problem constants (fixed by the reference)
#define NN 129
#define FF 262144
#define EE 16384
#define CHUNKS 32
#define CHUNK (FF / CHUNKS)   // 8192 floats per matvec block
#define NB 16                 // tail blocks: a*NB (reduction) + b/NB (atomics) min near 16
#define EPB (EE / NB)         // 1024 edges per block
#define EPT (EPB / 256)       // 4 edges per thread

// ws layout (doubles)
#define OFF_PARTIAL 0                              // [NN*CHUNKS] = 4128
#define OFF_DEGP    (OFF_PARTIAL + NN*CHUNKS)      // [NB*3*NN]
#define OFF_H1P     (OFF_DEGP + NB*3*NN)           // [NB*3*NN]
#define OFF_H2P     (OFF_H1P + NB*3*NN)            // [NB*3*NN]
#define OFF_BAR     (OFF_H2P + NB*3*NN)            // 4 uints (2 double slots), zeroed by memset node
// cnt[0] = matvec done-counter; cnt[1..3] = tail grid barriers

typedef float vfloat4 __attribute__((ext_vector_type(4)));

// ---------------------------------------------------------------------------
// Device-scope barrier for the NB tail blocks (counters zeroed by host memset).
// ---------------------------------------------------------------------------
__device__ __forceinline__ void gbar(unsigned* cnt, int idx) {
    __syncthreads();
    if (threadIdx.x == 0) {
        __threadfence();
        __hip_atomic_fetch_add(&cnt[idx], 1u, __ATOMIC_ACQ_REL, __HIP_MEMORY_SCOPE_AGENT);
        while (__hip_atomic_load(&cnt[idx], __ATOMIC_ACQUIRE, __HIP_MEMORY_SCOPE_AGENT) < (unsigned)NB)
            __builtin_amdgcn_s_sleep(1);
        __threadfence();
    }
    __syncthreads();
}

// ---------------------------------------------------------------------------
// Fused kernel. Blocks [0,NB): tail path (edges/degrees overlap matvec, then
// GCN phases + finale). Blocks [NB, NB+NN*CHUNKS): streaming matvec partials.
// Tail blocks are FIRST so their edge prefetch + degree partials + dinv all
// hide under the 135 MB x stream instead of running after it.
//
// LDS is time-aliased: one scratch region serves dp/hp (aggregation phases)
// and then the finale buffers, with maxpools fused into consumers (identical
// f64 op order => bit-exact vs the 2-kernel version). Static LDS ~22.9 KB
// keeps the streaming blocks at ~5-6 blocks/CU (plenty of bytes in flight).
// ---------------------------------------------------------------------------
__global__ __launch_bounds__(256) void k_fused(
    const float* __restrict__ x, const float* __restrict__ W,
    const int* __restrict__ eidx, const float* __restrict__ eattr,
    double* __restrict__ ws,
    const float* __restrict__ b1, const float* __restrict__ W2, const float* __restrict__ b2,
    const float* __restrict__ c1w, const float* __restrict__ c1b,
    const float* __restrict__ c2w, const float* __restrict__ c2b,
    const float* __restrict__ f1W, const float* __restrict__ f1b,
    const float* __restrict__ f2W, const float* __restrict__ f2b,
    const float* __restrict__ f3W, const float* __restrict__ f3b,
    float* __restrict__ out)
{
    const int b = blockIdx.x;
    const int tid = threadIdx.x;
    const int wave = tid >> 6, lane = tid & 63;

    // Persistent tail state
    __shared__ double P[129 + 387 + 387];     // sxw | sdinv[3][NN] | sh1[3][NN]
    // Time-aliased scratch (1917 doubles):
    //   phase A: dp/hp[4][3][NN] @0..1548
    //   finale:  z0@0(387) z1@387(387) c1o@774(1143) h2f@1161(387) rnk@1548(387 ints)
    //            c2o@0(369) allx@369(363)   (lifetimes disjoint, see phase comments)
    __shared__ double SCR[1917];
    __shared__ double ws4[4];                 // matvec wave partials
    __shared__ double fcb[38];                // fc1o[32] | fc2o[6]

    unsigned* cnt = (unsigned*)(ws + OFF_BAR);

    if (b >= NB) {
        // ---- Streaming matvec partial: one (row, chunk) dot-product block.
        // x non-temporal so the 135 MB stream doesn't evict W (L2-hot, 129x reuse).
        const int bm = b - NB;
        const int r = bm / CHUNKS, ch = bm % CHUNKS;
        const vfloat4* xp = (const vfloat4*)(x + (size_t)r * FF + (size_t)ch * CHUNK);
        const float4*  wp = (const float4*)(W + (size_t)ch * CHUNK);
        double acc0 = 0.0, acc1 = 0.0;
#pragma unroll
        for (int i = 0; i < CHUNK / (256 * 4); ++i) {   // 8 iters
            vfloat4 xv = __builtin_nontemporal_load(xp + tid + i * 256);
            float4  wv = wp[tid + i * 256];
            acc0 += (double)xv[0] * (double)wv.x + (double)xv[1] * (double)wv.y;
            acc1 += (double)xv[2] * (double)wv.z + (double)xv[3] * (double)wv.w;
        }
        double acc = acc0 + acc1;
        for (int off = 32; off > 0; off >>= 1) acc += __shfl_down(acc, off, 64);
        if (lane == 0) ws4[wave] = acc;
        __syncthreads();
        if (tid == 0) {
            ws[OFF_PARTIAL + bm] = (ws4[0] + ws4[1]) + (ws4[2] + ws4[3]);
            __threadfence();
            __hip_atomic_fetch_add(&cnt[0], 1u, __ATOMIC_ACQ_REL, __HIP_MEMORY_SCOPE_AGENT);
        }
        return;
    }

    // ======================== tail path (b in [0,NB)) ========================
    double* sxw   = P;            // [NN]
    double* sdinv = P + 129;      // [3*NN]
    double* sh1   = P + 516;      // [3*NN]
    double (*hp)[3][NN] = (double(*)[3][NN])SCR;   // also dp (degree partials)

    // ---- Prefetch this block's edge records FIRST (cold-miss latency hides
    // under the LDS zeroing below and the concurrent matvec stream).
    int er[EPT], ec[EPT];
    float ea[EPT][3];
#pragma unroll
    for (int i = 0; i < EPT; ++i) {
        const int e = b * EPB + i * 256 + tid;
        er[i] = eidx[e];
        ec[i] = eidx[EE + e];
        ea[i][0] = eattr[e * 3 + 0];
        ea[i][1] = eattr[e * 3 + 1];
        ea[i][2] = eattr[e * 3 + 2];
    }

    // ---- Degree partials (overlaps matvec stream)
    for (int i = tid; i < 4 * 3 * NN; i += 256) ((double*)hp)[i] = 0.0;
    __syncthreads();
#pragma unroll
    for (int i = 0; i < EPT; ++i) {
        const int cl = ec[i];
#pragma unroll
        for (int c = 0; c < 3; ++c)
            unsafeAtomicAdd(&hp[wave][c][cl], (double)ea[i][c]);
    }
    __syncthreads();
    for (int i = tid; i < 3 * NN; i += 256) {
        const int c = i / NN, j = i % NN;
        ws[OFF_DEGP + b * (3 * NN) + i] =
            (hp[0][c][j] + hp[1][c][j]) + (hp[2][c][j] + hp[3][c][j]);
    }
    gbar(cnt, 1);

    // ---- dinv (still overlapping matvec)
    for (int v = tid; v < 3 * NN; v += 256) {
        double d = 1.0;                                  // self loop weight
#pragma unroll
        for (int k = 0; k < NB; ++k) d += ws[OFF_DEGP + k * (3 * NN) + v];
        sdinv[v] = (d > 0.0) ? 1.0 / sqrt(d) : 0.0;
    }

    // ---- Wait for all matvec partials (same fence discipline as gbar)
    __syncthreads();
    if (tid == 0) {
        while (__hip_atomic_load(&cnt[0], __ATOMIC_ACQUIRE, __HIP_MEMORY_SCOPE_AGENT)
               < (unsigned)(NN * CHUNKS))
            __builtin_amdgcn_s_sleep(1);
        __threadfence();
    }
    __syncthreads();

    // ---- xw row sums (redundant per block; L2-warm reads)
    for (int j = tid; j < NN; j += 256) {
        double s = 0.0;
#pragma unroll
        for (int k = 0; k < CHUNKS; ++k) s += ws[OFF_PARTIAL + j * CHUNKS + k];
        sxw[j] = s;
    }
    for (int i = tid; i < 4 * 3 * NN; i += 256) ((double*)hp)[i] = 0.0;
    __syncthreads();

    // ---- Phase 1: layer-1 aggregation; norms cached in registers
    double enw[EPT][3];
#pragma unroll
    for (int i = 0; i < EPT; ++i) {
        const int r = er[i], cl = ec[i];
        const double xwr = sxw[r];
#pragma unroll
        for (int c = 0; c < 3; ++c) {
            const double nw = sdinv[c * NN + r] * (double)ea[i][c] * sdinv[c * NN + cl];
            enw[i][c] = nw;
            unsafeAtomicAdd(&hp[wave][c][cl], nw * xwr);
        }
    }
    __syncthreads();
    for (int i = tid; i < 3 * NN; i += 256) {
        const int c = i / NN, j = i % NN;
        ws[OFF_H1P + b * (3 * NN) + i] =
            (hp[0][c][j] + hp[1][c][j]) + (hp[2][c][j] + hp[3][c][j]);
    }
    gbar(cnt, 2);

    // ---- Phase 2: h1 (redundant per block)
    const double bb1 = (double)b1[0];
    for (int i = tid; i < 3 * NN; i += 256) {
        const int j = i % NN;
        const double dv = sdinv[i];
        double s = dv * dv * sxw[j] + bb1;
#pragma unroll
        for (int k = 0; k < NB; ++k) s += ws[OFF_H1P + k * (3 * NN) + i];
        sh1[i] = s;
    }
    for (int i = tid; i < 4 * 3 * NN; i += 256) ((double*)hp)[i] = 0.0;
    __syncthreads();

    // ---- Phase 3: layer-2 aggregation (same edges; register-cached norms)
    const double w2 = (double)W2[0];
#pragma unroll
    for (int i = 0; i < EPT; ++i) {
        const int r = er[i], cl = ec[i];
#pragma unroll
        for (int c = 0; c < 3; ++c)
            unsafeAtomicAdd(&hp[wave][c][cl], enw[i][c] * (sh1[c * NN + r] * w2));
    }
    __syncthreads();
    for (int i = tid; i < 3 * NN; i += 256) {
        const int c = i / NN, j = i % NN;
        ws[OFF_H2P + b * (3 * NN) + i] =
            (hp[0][c][j] + hp[1][c][j]) + (hp[2][c][j] + hp[3][c][j]);
    }
    gbar(cnt, 3);

    // ---- Finale: block 0 finishes the network
    if (b != 0) return;

    double* z0   = SCR;            // [3*NN]   live: z-fill .. conv1
    double* z1   = SCR + 387;      // [3*NN]   live: z-fill .. conv1
    double* c1o  = SCR + 774;      // [3*3*127] live: conv1 .. conv2
    double* h2f  = SCR + 1161;     // [3*NN]   live: h2 .. z-fill (dead before c1o write)
    int*    rnk  = (int*)(SCR + 1548);  // [3*NN] live: rank .. z-fill
    double* c2o  = SCR;            // [3*123]  live: conv2 .. pool (z dead by then)
    double* allx = SCR + 369;      // [363]    live: pool .. fc1
    double* fc1o = fcb;            // [32]
    double* fc2o = fcb + 32;       // [6]

    const double bb2 = (double)b2[0];
    for (int i = tid; i < 3 * NN; i += 256) {
        const int j = i % NN;
        const double dv = sdinv[i];
        double s = dv * dv * (sh1[i] * w2) + bb2;
#pragma unroll
        for (int k = 0; k < NB; ++k) s += ws[OFF_H2P + k * (3 * NN) + i];
        h2f[i] = s;
    }
    __syncthreads();

    // SortPool: stable argsort of -h2 (descending, ties by index), k = N
    for (int i = tid; i < 3 * NN; i += 256) {
        const int c = i / NN, j = i % NN;
        const double v = h2f[c * NN + j];
        int rk = 0;
        for (int q = 0; q < NN; ++q) {
            const double u = h2f[c * NN + q];
            rk += (u > v) || (u == v && q < j);
        }
        rnk[i] = rk;
    }
    __syncthreads();
    for (int i = tid; i < 3 * NN; i += 256) {
        const int c = i / NN;
        const int rk = rnk[i];
        z0[c * NN + rk] = sh1[i];
        z1[c * NN + rk] = h2f[i];
    }
    __syncthreads();

    // conv1 (in=2,out=3,k=3, VALID) -> 127   (h2f/rnk dead; c1o region free)
    for (int i = tid; i < 3 * 3 * 127; i += 256) {
        const int c = i / (3 * 127), rem = i % (3 * 127), o = rem / 127, p = rem % 127;
        double s = (double)c1b[o];
#pragma unroll
        for (int k = 0; k < 3; ++k) {
            s += (double)c1w[(o * 2 + 0) * 3 + k] * z0[c * NN + p + k];
            s += (double)c1w[(o * 2 + 1) * 3 + k] * z1[c * NN + p + k];
        }
        c1o[(c * 3 + o) * 127 + p] = s;
    }
    __syncthreads();

    // pool1 fused into conv2: p1o[c][ic][q] = max3(c1o[c][ic][q..q+2]); -> 123
    // (identical f64 op order to the materialized version)
    for (int i = tid; i < 3 * 123; i += 256) {
        const int c = i / 123, p = i % 123;
        double s = (double)c2b[0];
#pragma unroll
        for (int ic = 0; ic < 3; ++ic)
#pragma unroll
            for (int k = 0; k < 3; ++k) {
                const double* base = c1o + (c * 3 + ic) * 127 + p + k;
                const double m = fmax(base[0], fmax(base[1], base[2]));
                s += (double)c2w[ic * 3 + k] * m;
            }
        c2o[c * 123 + p] = s;
    }
    __syncthreads();
    for (int i = tid; i < 3 * 121; i += 256) {
        const int c = i / 121, p = i % 121;
        allx[c * 121 + p] = fmax(c2o[c * 123 + p],
                            fmax(c2o[c * 123 + p + 1], c2o[c * 123 + p + 2]));
    }
    __syncthreads();

    // fc1: 363 -> 32, ELU (8 lanes per output, aligned subgroups)
    {
        const int j = tid >> 3, t = tid & 7;
        double s = 0.0;
        for (int i = t; i < 363; i += 8) s += allx[i] * (double)f1W[i * 32 + j];
        s += __shfl_down(s, 4, 8);
        s += __shfl_down(s, 2, 8);
        s += __shfl_down(s, 1, 8);
        if (t == 0) {
            s += (double)f1b[j];
            fc1o[j] = (s > 0.0) ? s : expm1(s);
        }
    }
    __syncthreads();
    if (tid < 6) {
        double s = (double)f2b[tid];
        for (int i = 0; i < 32; ++i) s += fc1o[i] * (double)f2W[i * 6 + tid];
        fc2o[tid] = (s > 0.0) ? s : expm1(s);
    }
    __syncthreads();
    if (tid < 2) {
        double s = (double)f3b[tid];
        for (int i = 0; i < 6; ++i) s += fc2o[i] * (double)f3W[i * 2 + tid];
        out[tid] = (float)s;
    }
}

extern "C" void kernel_launch(void* const* d_in, const int* in_sizes, int n_in,
                              void* d_out, int out_size, void* d_ws, size_t ws_size,
                              hipStream_t stream) {
    const float* x    = (const float*)d_in[0];
    const int*   eidx = (const int*)d_in[1];
    const float* eattr= (const float*)d_in[2];
    const float* g1W  = (const float*)d_in[3];
    const float* g1b  = (const float*)d_in[4];
    const float* g2W  = (const float*)d_in[5];
    const float* g2b  = (const float*)d_in[6];
    const float* c1w  = (const float*)d_in[7];
    const float* c1b  = (const float*)d_in[8];
    const float* c2w  = (const float*)d_in[9];
    const float* c2b  = (const float*)d_in[10];
    const float* f1W  = (const float*)d_in[11];
    const float* f1b  = (const float*)d_in[12];
    const float* f2W  = (const float*)d_in[13];
    const float* f2b  = (const float*)d_in[14];
    const float* f3W  = (const float*)d_in[15];
    const float* f3b  = (const float*)d_in[16];
    float* out = (float*)d_out;
    double* ws = (double*)d_ws;

    // Zero done-counter + 3 tail barriers (ws is re-poisoned each iteration).
    hipMemsetAsync((void*)(ws + OFF_BAR), 0, 4 * sizeof(unsigned), stream);
    k_fused<<<NN * CHUNKS + NB, 256, 0, stream>>>(
        x, g1W, eidx, eattr, ws,
        g1b, g2W, g2b, c1w, c1b, c2w, c2b,
        f1W, f1b, f2W, f2b, f3W, f3b, out);
}

// Round 2
// 263.854 us; speedup vs baseline: 2.3689x; 2.3689x over previous
//
#include <hip/hip_runtime.h>
#include <hip/hip_bf16.h>
#include <math.h>

// Problem constants (fixed by the reference)
#define NN 129
#define FF 262144
#define EE 16384
#define CHUNKS 32
#define CHUNK (FF / CHUNKS)   // 8192 floats per matvec block
#define NB 16                 // tail blocks: a*NB (reduction) + b/NB (atomics) min near 16
#define EPB (EE / NB)         // 1024 edges per block
#define EPT (EPB / 256)       // 4 edges per thread
#define NMV (NN * CHUNKS)     // 4128 matvec blocks

// ws layout (doubles)
#define OFF_PARTIAL 0                              // [NN*CHUNKS] = 4128
#define OFF_DEGP    (OFF_PARTIAL + NN*CHUNKS)      // [NB*3*NN]
#define OFF_H1P     (OFF_DEGP + NB*3*NN)           // [NB*3*NN]
#define OFF_H2P     (OFF_H1P + NB*3*NN)            // [NB*3*NN]
#define OFF_BAR     (OFF_H2P + NB*3*NN)            // 67 cachelines x 128 B, zeroed by memset
// Sync region layout (128-B lines, LSTRIDE uints apart):
//   lines 0..63  : distributed matvec done-counters (bm & 63)
//   lines 64..66 : tail grid barriers 0..2
#define LSTRIDE 32            // uints per 128-B line

typedef float vfloat4 __attribute__((ext_vector_type(4)));

// ---------------------------------------------------------------------------
// Device-scope barrier for the NB tail blocks. Only 16 participants on a
// private cacheline -> no contention storm (same pattern ran fine in the
// 2-kernel k_rest at ~15 us).
// ---------------------------------------------------------------------------
__device__ __forceinline__ void gbar(unsigned* line) {
    __syncthreads();
    if (threadIdx.x == 0) {
        __threadfence();
        __hip_atomic_fetch_add(line, 1u, __ATOMIC_ACQ_REL, __HIP_MEMORY_SCOPE_AGENT);
        while (__hip_atomic_load(line, __ATOMIC_ACQUIRE, __HIP_MEMORY_SCOPE_AGENT) < (unsigned)NB)
            __builtin_amdgcn_s_sleep(1);
        __threadfence();
    }
    __syncthreads();
}

// ---------------------------------------------------------------------------
// Fused kernel. Blocks [0,NB): tail path. Blocks [NB, NB+NMV): matvec.
//
// Matvec -> tail handoff (the round-1 regression was here):
//   writer: relaxed AGENT atomic store of the partial (lands at the device
//           coherence point, no per-block L2 writeback), s_waitcnt vmcnt(0)
//           to order it, then relaxed RMW on 1-of-64 per-cacheline counters.
//   reader: 64 lanes spin on 64 distinct lines with s_sleep backoff, then
//           read partials with relaxed AGENT atomic loads.
// This removes the single contended cacheline (4128 ACQ_REL RMWs + 16
// spinners) and the per-block __threadfence that serialized round 1.
// ---------------------------------------------------------------------------
__global__ __launch_bounds__(256) void k_fused(
    const float* __restrict__ x, const float* __restrict__ W,
    const int* __restrict__ eidx, const float* __restrict__ eattr,
    double* __restrict__ ws,
    const float* __restrict__ b1, const float* __restrict__ W2, const float* __restrict__ b2,
    const float* __restrict__ c1w, const float* __restrict__ c1b,
    const float* __restrict__ c2w, const float* __restrict__ c2b,
    const float* __restrict__ f1W, const float* __restrict__ f1b,
    const float* __restrict__ f2W, const float* __restrict__ f2b,
    const float* __restrict__ f3W, const float* __restrict__ f3b,
    float* __restrict__ out)
{
    const int b = blockIdx.x;
    const int tid = threadIdx.x;
    const int wave = tid >> 6, lane = tid & 63;

    // Persistent tail state
    __shared__ double P[129 + 387 + 387];     // sxw | sdinv[3][NN] | sh1[3][NN]
    // Time-aliased scratch (1917 doubles): dp/hp in aggregation phases,
    // finale buffers afterwards (disjoint lifetimes).
    __shared__ double SCR[1917];
    __shared__ double ws4[4];                 // matvec wave partials
    __shared__ double fcb[38];                // fc1o[32] | fc2o[6]

    unsigned* sync = (unsigned*)(ws + OFF_BAR);

    if (b >= NB) {
        // ---- Streaming matvec partial: one (row, chunk) dot-product block.
        // x non-temporal so the 135 MB stream doesn't evict W (L2-hot, 129x reuse).
        const int bm = b - NB;
        const int r = bm / CHUNKS, ch = bm % CHUNKS;
        const vfloat4* xp = (const vfloat4*)(x + (size_t)r * FF + (size_t)ch * CHUNK);
        const float4*  wp = (const float4*)(W + (size_t)ch * CHUNK);
        double acc0 = 0.0, acc1 = 0.0;
#pragma unroll
        for (int i = 0; i < CHUNK / (256 * 4); ++i) {   // 8 iters
            vfloat4 xv = __builtin_nontemporal_load(xp + tid + i * 256);
            float4  wv = wp[tid + i * 256];
            acc0 += (double)xv[0] * (double)wv.x + (double)xv[1] * (double)wv.y;
            acc1 += (double)xv[2] * (double)wv.z + (double)xv[3] * (double)wv.w;
        }
        double acc = acc0 + acc1;
        for (int off = 32; off > 0; off >>= 1) acc += __shfl_down(acc, off, 64);
        if (lane == 0) ws4[wave] = acc;
        __syncthreads();
        if (tid == 0) {
            const double v = (ws4[0] + ws4[1]) + (ws4[2] + ws4[3]);
            // coherence-point store; no L2 writeback needed
            __hip_atomic_store(&ws[OFF_PARTIAL + bm], v,
                               __ATOMIC_RELAXED, __HIP_MEMORY_SCOPE_AGENT);
            asm volatile("s_waitcnt vmcnt(0)" ::: "memory");  // order store before signal
            __hip_atomic_fetch_add(&sync[(bm & 63) * LSTRIDE], 1u,
                                   __ATOMIC_RELAXED, __HIP_MEMORY_SCOPE_AGENT);
        }
        return;
    }

    // ======================== tail path (b in [0,NB)) ========================
    double* sxw   = P;            // [NN]
    double* sdinv = P + 129;      // [3*NN]
    double* sh1   = P + 516;      // [3*NN]
    double (*hp)[3][NN] = (double(*)[3][NN])SCR;   // also dp (degree partials)

    // ---- Prefetch this block's edge records FIRST (cold-miss latency hides
    // under the LDS zeroing below and the concurrent matvec stream).
    int er[EPT], ec[EPT];
    float ea[EPT][3];
#pragma unroll
    for (int i = 0; i < EPT; ++i) {
        const int e = b * EPB + i * 256 + tid;
        er[i] = eidx[e];
        ec[i] = eidx[EE + e];
        ea[i][0] = eattr[e * 3 + 0];
        ea[i][1] = eattr[e * 3 + 1];
        ea[i][2] = eattr[e * 3 + 2];
    }

    // ---- Degree partials (overlaps matvec stream)
    for (int i = tid; i < 4 * 3 * NN; i += 256) ((double*)hp)[i] = 0.0;
    __syncthreads();
#pragma unroll
    for (int i = 0; i < EPT; ++i) {
        const int cl = ec[i];
#pragma unroll
        for (int c = 0; c < 3; ++c)
            unsafeAtomicAdd(&hp[wave][c][cl], (double)ea[i][c]);
    }
    __syncthreads();
    for (int i = tid; i < 3 * NN; i += 256) {
        const int c = i / NN, j = i % NN;
        ws[OFF_DEGP + b * (3 * NN) + i] =
            (hp[0][c][j] + hp[1][c][j]) + (hp[2][c][j] + hp[3][c][j]);
    }
    gbar(sync + 64 * LSTRIDE);

    // ---- dinv (still overlapping matvec)
    for (int v = tid; v < 3 * NN; v += 256) {
        double d = 1.0;                                  // self loop weight
#pragma unroll
        for (int k = 0; k < NB; ++k) d += ws[OFF_DEGP + k * (3 * NN) + v];
        sdinv[v] = (d > 0.0) ? 1.0 / sqrt(d) : 0.0;
    }
    __syncthreads();

    // ---- Wait for all matvec partials: 64 lanes, 64 private cachelines.
    // Expected per-residue counts: 4128 = 64*64 + 32 -> lanes 0..31 see 65.
    if (tid < 64) {
        unsigned* c = sync + tid * LSTRIDE;
        const unsigned expct = (tid < 32) ? 65u : 64u;
        while (__hip_atomic_load(c, __ATOMIC_RELAXED, __HIP_MEMORY_SCOPE_AGENT) < expct)
            __builtin_amdgcn_s_sleep(32);
    }
    __syncthreads();

    // ---- xw row sums (coherence-point reads; writers stored with sc-bits)
    for (int j = tid; j < NN; j += 256) {
        double s = 0.0;
#pragma unroll
        for (int k = 0; k < CHUNKS; ++k)
            s += __hip_atomic_load(&ws[OFF_PARTIAL + j * CHUNKS + k],
                                   __ATOMIC_RELAXED, __HIP_MEMORY_SCOPE_AGENT);
        sxw[j] = s;
    }
    for (int i = tid; i < 4 * 3 * NN; i += 256) ((double*)hp)[i] = 0.0;
    __syncthreads();

    // ---- Phase 1: layer-1 aggregation; norms cached in registers
    double enw[EPT][3];
#pragma unroll
    for (int i = 0; i < EPT; ++i) {
        const int r = er[i], cl = ec[i];
        const double xwr = sxw[r];
#pragma unroll
        for (int c = 0; c < 3; ++c) {
            const double nw = sdinv[c * NN + r] * (double)ea[i][c] * sdinv[c * NN + cl];
            enw[i][c] = nw;
            unsafeAtomicAdd(&hp[wave][c][cl], nw * xwr);
        }
    }
    __syncthreads();
    for (int i = tid; i < 3 * NN; i += 256) {
        const int c = i / NN, j = i % NN;
        ws[OFF_H1P + b * (3 * NN) + i] =
            (hp[0][c][j] + hp[1][c][j]) + (hp[2][c][j] + hp[3][c][j]);
    }
    gbar(sync + 65 * LSTRIDE);

    // ---- Phase 2: h1 (redundant per block)
    const double bb1 = (double)b1[0];
    for (int i = tid; i < 3 * NN; i += 256) {
        const int j = i % NN;
        const double dv = sdinv[i];
        double s = dv * dv * sxw[j] + bb1;
#pragma unroll
        for (int k = 0; k < NB; ++k) s += ws[OFF_H1P + k * (3 * NN) + i];
        sh1[i] = s;
    }
    for (int i = tid; i < 4 * 3 * NN; i += 256) ((double*)hp)[i] = 0.0;
    __syncthreads();

    // ---- Phase 3: layer-2 aggregation (same edges; register-cached norms)
    const double w2 = (double)W2[0];
#pragma unroll
    for (int i = 0; i < EPT; ++i) {
        const int r = er[i], cl = ec[i];
#pragma unroll
        for (int c = 0; c < 3; ++c)
            unsafeAtomicAdd(&hp[wave][c][cl], enw[i][c] * (sh1[c * NN + r] * w2));
    }
    __syncthreads();
    for (int i = tid; i < 3 * NN; i += 256) {
        const int c = i / NN, j = i % NN;
        ws[OFF_H2P + b * (3 * NN) + i] =
            (hp[0][c][j] + hp[1][c][j]) + (hp[2][c][j] + hp[3][c][j]);
    }
    gbar(sync + 66 * LSTRIDE);

    // ---- Finale: block 0 finishes the network
    if (b != 0) return;

    double* z0   = SCR;            // [3*NN]   live: z-fill .. conv1
    double* z1   = SCR + 387;      // [3*NN]   live: z-fill .. conv1
    double* c1o  = SCR + 774;      // [3*3*127] live: conv1 .. conv2
    double* h2f  = SCR + 1161;     // [3*NN]   live: h2 .. z-fill
    int*    rnk  = (int*)(SCR + 1548);  // [3*NN] live: rank .. z-fill
    double* c2o  = SCR;            // [3*123]  live: conv2 .. pool (z dead by then)
    double* allx = SCR + 369;      // [363]    live: pool .. fc1
    double* fc1o = fcb;            // [32]
    double* fc2o = fcb + 32;       // [6]

    const double bb2 = (double)b2[0];
    for (int i = tid; i < 3 * NN; i += 256) {
        const int j = i % NN;
        const double dv = sdinv[i];
        double s = dv * dv * (sh1[i] * w2) + bb2;
#pragma unroll
        for (int k = 0; k < NB; ++k) s += ws[OFF_H2P + k * (3 * NN) + i];
        h2f[i] = s;
    }
    __syncthreads();

    // SortPool: stable argsort of -h2 (descending, ties by index), k = N
    for (int i = tid; i < 3 * NN; i += 256) {
        const int c = i / NN, j = i % NN;
        const double v = h2f[c * NN + j];
        int rk = 0;
        for (int q = 0; q < NN; ++q) {
            const double u = h2f[c * NN + q];
            rk += (u > v) || (u == v && q < j);
        }
        rnk[i] = rk;
    }
    __syncthreads();
    for (int i = tid; i < 3 * NN; i += 256) {
        const int c = i / NN;
        const int rk = rnk[i];
        z0[c * NN + rk] = sh1[i];
        z1[c * NN + rk] = h2f[i];
    }
    __syncthreads();

    // conv1 (in=2,out=3,k=3, VALID) -> 127   (h2f/rnk dead; c1o region free)
    for (int i = tid; i < 3 * 3 * 127; i += 256) {
        const int c = i / (3 * 127), rem = i % (3 * 127), o = rem / 127, p = rem % 127;
        double s = (double)c1b[o];
#pragma unroll
        for (int k = 0; k < 3; ++k) {
            s += (double)c1w[(o * 2 + 0) * 3 + k] * z0[c * NN + p + k];
            s += (double)c1w[(o * 2 + 1) * 3 + k] * z1[c * NN + p + k];
        }
        c1o[(c * 3 + o) * 127 + p] = s;
    }
    __syncthreads();

    // pool1 fused into conv2 (identical f64 op order to materialized version)
    for (int i = tid; i < 3 * 123; i += 256) {
        const int c = i / 123, p = i % 123;
        double s = (double)c2b[0];
#pragma unroll
        for (int ic = 0; ic < 3; ++ic)
#pragma unroll
            for (int k = 0; k < 3; ++k) {
                const double* base = c1o + (c * 3 + ic) * 127 + p + k;
                const double m = fmax(base[0], fmax(base[1], base[2]));
                s += (double)c2w[ic * 3 + k] * m;
            }
        c2o[c * 123 + p] = s;
    }
    __syncthreads();
    for (int i = tid; i < 3 * 121; i += 256) {
        const int c = i / 121, p = i % 121;
        allx[c * 121 + p] = fmax(c2o[c * 123 + p],
                            fmax(c2o[c * 123 + p + 1], c2o[c * 123 + p + 2]));
    }
    __syncthreads();

    // fc1: 363 -> 32, ELU (8 lanes per output, aligned subgroups)
    {
        const int j = tid >> 3, t = tid & 7;
        double s = 0.0;
        for (int i = t; i < 363; i += 8) s += allx[i] * (double)f1W[i * 32 + j];
        s += __shfl_down(s, 4, 8);
        s += __shfl_down(s, 2, 8);
        s += __shfl_down(s, 1, 8);
        if (t == 0) {
            s += (double)f1b[j];
            fc1o[j] = (s > 0.0) ? s : expm1(s);
        }
    }
    __syncthreads();
    if (tid < 6) {
        double s = (double)f2b[tid];
        for (int i = 0; i < 32; ++i) s += fc1o[i] * (double)f2W[i * 6 + tid];
        fc2o[tid] = (s > 0.0) ? s : expm1(s);
    }
    __syncthreads();
    if (tid < 2) {
        double s = (double)f3b[tid];
        for (int i = 0; i < 6; ++i) s += fc2o[i] * (double)f3W[i * 2 + tid];
        out[tid] = (float)s;
    }
}

extern "C" void kernel_launch(void* const* d_in, const int* in_sizes, int n_in,
                              void* d_out, int out_size, void* d_ws, size_t ws_size,
                              hipStream_t stream) {
    const float* x    = (const float*)d_in[0];
    const int*   eidx = (const int*)d_in[1];
    const float* eattr= (const float*)d_in[2];
    const float* g1W  = (const float*)d_in[3];
    const float* g1b  = (const float*)d_in[4];
    const float* g2W  = (const float*)d_in[5];
    const float* g2b  = (const float*)d_in[6];
    const float* c1w  = (const float*)d_in[7];
    const float* c1b  = (const float*)d_in[8];
    const float* c2w  = (const float*)d_in[9];
    const float* c2b  = (const float*)d_in[10];
    const float* f1W  = (const float*)d_in[11];
    const float* f1b  = (const float*)d_in[12];
    const float* f2W  = (const float*)d_in[13];
    const float* f2b  = (const float*)d_in[14];
    const float* f3W  = (const float*)d_in[15];
    const float* f3b  = (const float*)d_in[16];
    float* out = (float*)d_out;
    double* ws = (double*)d_ws;

    // Zero the 67-cacheline sync region (ws is re-poisoned each iteration).
    hipMemsetAsync((void*)(ws + OFF_BAR), 0, 67 * 128, stream);
    k_fused<<<NN * CHUNKS + NB, 256, 0, stream>>>(
        x, g1W, eidx, eattr, ws,
        g1b, g2W, g2b, c1w, c1b, c2w, c2b,
        f1W, f1b, f2W, f2b, f3W, f3b, out);
}